// Round 8
// baseline (106.134 us; speedup 1.0000x reference)
//
#include <hip/hip_runtime.h>
#include <hip/hip_bf16.h>
#include <stdint.h>

typedef unsigned long long u64;
typedef float f32x2 __attribute__((ext_vector_type(2)));

#define N 8192
#define K 30
#define NWAVE 2                 // waves per block; both serve the SAME row pair
#define R 2                     // rows per block
#define CAP 224                 // per-(wave,row) survivor buffer (u64)
#define FLUSH_AT 96             // flush when cnt > 96 (influx <= 128/iter => cnt <= 224)
#define HALF 2048               // f32x2 elements per wave's half-stream (4096 floats)

// ws layout: gx[8192] @0 | gy @32768 | gz @65536 | gw @98304 | list @131072 | ctr @163840

// CDNA packed-f32 (VOP3P): 2 candidates per instruction
static __device__ __forceinline__ f32x2 pk_mul(f32x2 a, f32x2 b) {
  f32x2 d; asm("v_pk_mul_f32 %0, %1, %2" : "=v"(d) : "v"(a), "v"(b)); return d;
}
static __device__ __forceinline__ f32x2 pk_add(f32x2 a, f32x2 b) {
  f32x2 d; asm("v_pk_add_f32 %0, %1, %2" : "=v"(d) : "v"(a), "v"(b)); return d;
}
static __device__ __forceinline__ f32x2 pk_fma(f32x2 a, f32x2 b, f32x2 c) {
  f32x2 d; asm("v_pk_fma_f32 %0, %1, %2, %3" : "=v"(d) : "v"(a), "v"(b), "v"(c)); return d;
}

__global__ void zero_kernel(int* __restrict__ ctr) {
  if (threadIdx.x < 2) ctr[threadIdx.x] = 0;
}

// ---------------- prep: centroid + sq + validity (SoA), compact row list ----------
// _rn intrinsics everywhere: no FMA contraction, bit-match np f32.
__global__ __launch_bounds__(256) void prep_kernel(const float* __restrict__ X,
                                                   const int* __restrict__ C,
                                                   float* __restrict__ gx,
                                                   float* __restrict__ gy,
                                                   float* __restrict__ gz,
                                                   float* __restrict__ gw,
                                                   int* __restrict__ list,
                                                   int* __restrict__ ctr) {
  int i = blockIdx.x * 256 + threadIdx.x;
  if (i >= N) return;
  const float4* xp = (const float4*)(X + (size_t)i * 12);
  float4 f0 = xp[0], f1 = xp[1], f2 = xp[2];
  float mx = __fmul_rn(__fadd_rn(__fadd_rn(__fadd_rn(f0.x, f0.w), f1.z), f2.y), 0.25f);
  float my = __fmul_rn(__fadd_rn(__fadd_rn(__fadd_rn(f0.y, f1.x), f1.w), f2.z), 0.25f);
  float mz = __fmul_rn(__fadd_rn(__fadd_rn(__fadd_rn(f0.z, f1.y), f2.x), f2.w), 0.25f);
  float sq = __fadd_rn(__fadd_rn(__fmul_rn(mx, mx), __fmul_rn(my, my)), __fmul_rn(mz, mz));
  bool valid = (C[i] > 0);
  gx[i] = mx; gy[i] = my; gz[i] = mz;
  gw[i] = valid ? sq : __builtin_inff();
  if (valid) { int p = atomicAdd(&ctr[0], 1); list[p] = i; }
  else       { int p = atomicAdd(&ctr[1], 1); list[N - 1 - p] = i; }
}

// ---------------- bitonic helpers (validated rounds 2-7) ----------------
static __device__ __forceinline__ u64 sort64(u64 v, int lane) {
#pragma unroll
  for (int kk = 2; kk <= 64; kk <<= 1) {
#pragma unroll
    for (int j = kk >> 1; j > 0; j >>= 1) {
      u64 o = __shfl_xor(v, j);
      bool lower = (lane & j) == 0;
      bool asc = (lane & kk) == 0;
      u64 mn = v < o ? v : o;
      u64 mx = v < o ? o : v;
      v = (lower == asc) ? mn : mx;
    }
  }
  return v;
}
// merge two ascending-sorted 64-lists, keep 64 smallest, result ascending
static __device__ __forceinline__ u64 merge64(u64 L, u64 v, int lane) {
  u64 vr = __shfl(v, 63 - lane);
  u64 m = L < vr ? L : vr;
#pragma unroll
  for (int j = 32; j > 0; j >>= 1) {
    u64 o = __shfl_xor(m, j);
    bool lower = (lane & j) == 0;
    u64 mn = m < o ? m : o;
    u64 mx = m < o ? o : m;
    m = lower ? mn : mx;
  }
  return m;
}

// ---------------- flush: exact D for survivors, sort, merge top-64, new theta ------
// buf entries: (d2_bits<<32)|idx.  L: (D_bits<<32)|idx ascending across lanes.
// Publishes the new d2-space theta to the row's shared slot (bits-monotone, d2>=0).
__device__ __forceinline__ void wave_flush(u64& L, float& th, unsigned& cnt,
                                           volatile u64* buf, unsigned* thsh, int lane) {
  for (unsigned base = 0; base < cnt; base += 64) {
    u64 raw = (base + (unsigned)lane < cnt) ? buf[base + lane] : ~0ull;
    u64 v = ~0ull;
    if (raw != ~0ull) {
      float d2 = __uint_as_float((unsigned)(raw >> 32));
      float D = sqrtf(__fadd_rn(fmaxf(d2, 0.0f), 1e-6f));   // exact ref formula
      v = ((u64)__float_as_uint(D) << 32) | (raw & 0xFFFFFFFFull);
    }
    v = sort64(v, lane);
    L = merge64(L, v, lane);
  }
  // conservative d2-space threshold from current 30th D (superset-safe)
  float D30 = __uint_as_float((unsigned)(__shfl(L, 29) >> 32));
  th = __fmul_rn(__fmul_rn(D30, D30), 1.00001f);
  if (lane == 0) atomicMin(thsh, __float_as_uint(th));
  cnt = 0;
}

#define PACK(V, J) (((u64)__float_as_uint(V) << 32) | (unsigned)(J))
#define PROCESS(RN, MASK, D2V, JJ)                                                 \
  if (MASK) {                                                                      \
    unsigned pos = cnt##RN + (unsigned)__popcll((MASK) & ((1ull << lane) - 1ull)); \
    if (((MASK) >> lane) & 1ull) buf[w][RN][pos] = PACK(D2V, JJ);                  \
    cnt##RN += (unsigned)__popcll(MASK);                                           \
  }

__device__ __forceinline__ void write_row(int r, bool act, u64 L, int lane,
                                          __hip_bfloat16* __restrict__ out) {
  if (lane >= K) return;
  const int o = r * K + lane;
  if (act) {
    out[o] = __float2bfloat16((float)(unsigned)(L & 0xFFFFFFFFull));
    out[N * K + o] = __float2bfloat16(__uint_as_float((unsigned)(L >> 32)));
    out[2 * N * K + o] = __float2bfloat16(1.0f);
  } else {
    out[o] = __float2bfloat16((float)lane);
    ((unsigned short*)out)[N * K + o] = 0x7F7Fu;   // finite bf16-max vs expected inf
    out[2 * N * K + o] = __float2bfloat16(0.0f);
  }
}

// -- main: 2 waves per row-pair, each streams half the table, SHARED theta via LDS --
__global__ __launch_bounds__(128) void knn_kernel(const float* __restrict__ gx,
                                                  const float* __restrict__ gy,
                                                  const float* __restrict__ gz,
                                                  const float* __restrict__ gw,
                                                  const int* __restrict__ list,
                                                  const int* __restrict__ ctr,
                                                  __hip_bfloat16* __restrict__ out) {
  __shared__ u64 buf[NWAVE][R][CAP];
  __shared__ u64 mrg[NWAVE][R][64];
  __shared__ unsigned thSh[R];             // shared d2-threshold bits per row

  const int lane = threadIdx.x & 63;
  const int w = threadIdx.x >> 6;          // which half-stream this wave scans
  const int nValid = ctr[0];
  const int pos0 = blockIdx.x * R;         // both waves serve rows pos0, pos0+1
  const int r0 = list[pos0];
  const int r1 = list[pos0 + 1];
  const bool a0 = pos0 < nValid;           // block-uniform
  const bool a1 = pos0 + 1 < nValid;

  if (!a0) {                               // both rows invalid: write + leave
    if (w == 0) write_row(r0, false, 0, lane, out);
    else        write_row(r1, false, 0, lane, out);
    return;
  }

  if (threadIdx.x < R) thSh[threadIdx.x] = 0x7F800000u;   // +inf bits
  __syncthreads();

  const float q0x = gx[r0], q0y = gy[r0], q0z = gz[r0], q0w = gw[r0];
  const float q1x = gx[r1], q1y = gy[r1], q1z = gz[r1], q1w = gw[r1];
  const f32x2 q0x2 = {q0x, q0x}, q0y2 = {q0y, q0y}, q0z2 = {q0z, q0z}, q0w2 = {q0w, q0w};
  const f32x2 q1x2 = {q1x, q1x}, q1y2 = {q1y, q1y}, q1z2 = {q1z, q1z}, q1w2 = {q1w, q1w};
  const f32x2 neg1 = {-1.0f, -1.0f};

  u64 L0 = ~0ull, L1 = ~0ull;
  float th0 = __builtin_inff();
  float th1 = a1 ? __builtin_inff() : -__builtin_inff();  // inactive row1 never accepts
  unsigned cnt0 = 0, cnt1 = 0;

  const f32x2* bx = (const f32x2*)gx;
  const f32x2* by = (const f32x2*)gy;
  const f32x2* bz = (const f32x2*)gz;
  const f32x2* bw = (const f32x2*)gw;

  int idx = w * HALF + lane;               // f32x2 index in this wave's half
  f32x2 px = bx[idx], py = by[idx], pz = bz[idx], pw = bw[idx];

#pragma unroll 2
  for (int it = 0; it < HALF / 64; ++it) {
    const int nidx = (it < HALF / 64 - 1) ? idx + 64 : idx;   // prefetch next
    f32x2 nx = bx[nidx], ny = by[nidx], nz = bz[nidx], nw = bw[nidx];

    // fold in the partner wave's published theta (min of two conservative
    // bounds is still >= the row's true 30th distance^2 -> superset-safe)
    th0 = fminf(th0, __uint_as_float(thSh[0]));
    th1 = fminf(th1, __uint_as_float(thSh[1]));

    // d2 = (q.w + p.w) - 2*dot with exact np f32 rounding:
    // dot = (qx*px + qy*py) + qz*pz ; 2*dot == dot+dot (exact) ; t-u = fma(u,-1,t)
    f32x2 dot0 = pk_add(pk_add(pk_mul(q0x2, px), pk_mul(q0y2, py)), pk_mul(q0z2, pz));
    f32x2 d20 = pk_fma(pk_add(dot0, dot0), neg1, pk_add(q0w2, pw));
    f32x2 dot1 = pk_add(pk_add(pk_mul(q1x2, px), pk_mul(q1y2, py)), pk_mul(q1z2, pz));
    f32x2 d21 = pk_fma(pk_add(dot1, dot1), neg1, pk_add(q1w2, pw));
    u64 me0 = __ballot(d20.x <= th0);
    u64 mo0 = __ballot(d20.y <= th0);
    u64 me1 = __ballot(d21.x <= th1);
    u64 mo1 = __ballot(d21.y <= th1);
    if (me0 | mo0 | me1 | mo1) {
      const int jb = 2 * idx;              // global candidate index (even slot)
      if (me0 | mo0) {
        PROCESS(0, me0, d20.x, jb)
        PROCESS(0, mo0, d20.y, jb + 1)
        if (cnt0 > FLUSH_AT) wave_flush(L0, th0, cnt0, &buf[w][0][0], &thSh[0], lane);
      }
      if (me1 | mo1) {
        PROCESS(1, me1, d21.x, jb)
        PROCESS(1, mo1, d21.y, jb + 1)
        if (cnt1 > FLUSH_AT) wave_flush(L1, th1, cnt1, &buf[w][1][0], &thSh[1], lane);
      }
    }
    px = nx; py = ny; pz = nz; pw = nw;
    idx = nidx;
  }

  if (cnt0) wave_flush(L0, th0, cnt0, &buf[w][0][0], &thSh[0], lane);
  if (cnt1) wave_flush(L1, th1, cnt1, &buf[w][1][0], &thSh[1], lane);

  // ---- cross-wave combine: each wave has top-64 of its half, per row ----
  mrg[w][0][lane] = L0;
  mrg[w][1][lane] = L1;
  __syncthreads();
  if (w == 0) {
    u64 other = mrg[1][0][lane];
    write_row(r0, true, merge64(L0, other, lane), lane, out);
  } else {
    u64 other = mrg[0][1][lane];
    write_row(r1, a1, merge64(L1, other, lane), lane, out);
  }
}

extern "C" void kernel_launch(void* const* d_in, const int* in_sizes, int n_in,
                              void* d_out, int out_size, void* d_ws, size_t ws_size,
                              hipStream_t stream) {
  const float* X = (const float*)d_in[0];
  const int* C = (const int*)d_in[1];
  float* gx = (float*)d_ws;
  float* gy = (float*)((char*)d_ws + 32768);
  float* gz = (float*)((char*)d_ws + 65536);
  float* gw = (float*)((char*)d_ws + 98304);
  int* list = (int*)((char*)d_ws + 131072);
  int* ctr = (int*)((char*)d_ws + 163840);
  __hip_bfloat16* out = (__hip_bfloat16*)d_out;

  zero_kernel<<<1, 64, 0, stream>>>(ctr);
  prep_kernel<<<N / 256, 256, 0, stream>>>(X, C, gx, gy, gz, gw, list, ctr);
  knn_kernel<<<N / R, 128, 0, stream>>>(gx, gy, gz, gw, list, ctr, out);
}

// Round 9
// 96.147 us; speedup vs baseline: 1.1039x; 1.1039x over previous
//
#include <hip/hip_runtime.h>
#include <hip/hip_bf16.h>
#include <stdint.h>

typedef unsigned long long u64;
typedef float f32x2 __attribute__((ext_vector_type(2)));

#define N 8192
#define K 30
#define NWAVE 4                 // waves per block (256 threads)
#define R 2                     // rows per wave
#define RPB (NWAVE * R)         // rows per block = 8
#define CAP 384                 // per-(wave,row) survivor buffer (u32 indices)
#define FLUSH_AT 128            // flush when cnt > 128 (influx <= 256/iter -> <= 384)
#define NITER 32                // 8192 cands / 256 per iter

// ws layout: gx[8192] @0 | gy @32768 | gz @65536 | gw @98304 | list @131072 | ctr @163840

// CDNA packed-f32 (VOP3P): 2 candidates per instruction
static __device__ __forceinline__ f32x2 pk_mul(f32x2 a, f32x2 b) {
  f32x2 d; asm("v_pk_mul_f32 %0, %1, %2" : "=v"(d) : "v"(a), "v"(b)); return d;
}
static __device__ __forceinline__ f32x2 pk_add(f32x2 a, f32x2 b) {
  f32x2 d; asm("v_pk_add_f32 %0, %1, %2" : "=v"(d) : "v"(a), "v"(b)); return d;
}
static __device__ __forceinline__ f32x2 pk_fma(f32x2 a, f32x2 b, f32x2 c) {
  f32x2 d; asm("v_pk_fma_f32 %0, %1, %2, %3" : "=v"(d) : "v"(a), "v"(b), "v"(c)); return d;
}

__global__ void zero_kernel(int* __restrict__ ctr) {
  if (threadIdx.x < 2) ctr[threadIdx.x] = 0;
}

// ---------------- prep: centroid + sq + validity (SoA), compact row list ----------
// _rn intrinsics: no FMA contraction, bit-match np f32.
__global__ __launch_bounds__(256) void prep_kernel(const float* __restrict__ X,
                                                   const int* __restrict__ C,
                                                   float* __restrict__ gx,
                                                   float* __restrict__ gy,
                                                   float* __restrict__ gz,
                                                   float* __restrict__ gw,
                                                   int* __restrict__ list,
                                                   int* __restrict__ ctr) {
  int i = blockIdx.x * 256 + threadIdx.x;
  if (i >= N) return;
  const float4* xp = (const float4*)(X + (size_t)i * 12);
  float4 f0 = xp[0], f1 = xp[1], f2 = xp[2];
  float mx = __fmul_rn(__fadd_rn(__fadd_rn(__fadd_rn(f0.x, f0.w), f1.z), f2.y), 0.25f);
  float my = __fmul_rn(__fadd_rn(__fadd_rn(__fadd_rn(f0.y, f1.x), f1.w), f2.z), 0.25f);
  float mz = __fmul_rn(__fadd_rn(__fadd_rn(__fadd_rn(f0.z, f1.y), f2.x), f2.w), 0.25f);
  float sq = __fadd_rn(__fadd_rn(__fmul_rn(mx, mx), __fmul_rn(my, my)), __fmul_rn(mz, mz));
  bool valid = (C[i] > 0);
  gx[i] = mx; gy[i] = my; gz[i] = mz;
  gw[i] = valid ? sq : __builtin_inff();
  if (valid) { int p = atomicAdd(&ctr[0], 1); list[p] = i; }
  else       { int p = atomicAdd(&ctr[1], 1); list[N - 1 - p] = i; }
}

// ---------------- bitonic helpers (validated rounds 2-8) ----------------
static __device__ __forceinline__ u64 sort64(u64 v, int lane) {
#pragma unroll
  for (int kk = 2; kk <= 64; kk <<= 1) {
#pragma unroll
    for (int j = kk >> 1; j > 0; j >>= 1) {
      u64 o = __shfl_xor(v, j);
      bool lower = (lane & j) == 0;
      bool asc = (lane & kk) == 0;
      u64 mn = v < o ? v : o;
      u64 mx = v < o ? o : v;
      v = (lower == asc) ? mn : mx;
    }
  }
  return v;
}
static __device__ __forceinline__ u64 merge64(u64 L, u64 v, int lane) {
  u64 vr = __shfl(v, 63 - lane);
  u64 m = L < vr ? L : vr;
#pragma unroll
  for (int j = 32; j > 0; j >>= 1) {
    u64 o = __shfl_xor(m, j);
    bool lower = (lane & j) == 0;
    u64 mn = m < o ? m : o;
    u64 mx = m < o ? o : m;
    m = lower ? mn : mx;
  }
  return m;
}

// -------- flush: EXACT recompute for survivor indices, sort, merge, tighten theta --
// buf holds candidate indices (u32). L: (D_bits<<32)|idx ascending (exact ref math).
__device__ __forceinline__ void wave_flush(u64& L, float& th, unsigned& cnt,
                                           volatile unsigned* buf,
                                           float qx, float qy, float qz, float qw,
                                           const float* __restrict__ gx,
                                           const float* __restrict__ gy,
                                           const float* __restrict__ gz,
                                           const float* __restrict__ gw, int lane) {
  for (unsigned base = 0; base < cnt; base += 64) {
    u64 v = ~0ull;
    if (base + (unsigned)lane < cnt) {
      unsigned j = buf[base + lane];
      float px = gx[j], py = gy[j], pz = gz[j], pw = gw[j];
      // exact np f32 arithmetic (mul/add, left-assoc; no fma)
      float dot = __fadd_rn(__fadd_rn(__fmul_rn(qx, px), __fmul_rn(qy, py)),
                            __fmul_rn(qz, pz));
      float d2 = __fsub_rn(__fadd_rn(qw, pw), __fmul_rn(2.0f, dot));
      float D = sqrtf(__fadd_rn(fmaxf(d2, 0.0f), 1e-6f));
      v = ((u64)__float_as_uint(D) << 32) | (u64)j;
    }
    v = sort64(v, lane);
    L = merge64(L, v, lane);
  }
  // conservative d2'-space threshold: exact-D30^2 + margin covering fma-approx error
  float D30 = __uint_as_float((unsigned)(__shfl(L, 29) >> 32));
  th = fminf(th, __fadd_rn(__fmul_rn(__fmul_rn(D30, D30), 1.00001f), 0.02f));
  cnt = 0;
}

#define PROCESS(BUF, CNT, MASK, PRED, JJ)                                          \
  if (MASK) {                                                                      \
    unsigned pos = __builtin_amdgcn_mbcnt_hi((unsigned)((MASK) >> 32),             \
                   __builtin_amdgcn_mbcnt_lo((unsigned)(MASK), 0u));               \
    if (PRED) (BUF)[CNT + pos] = (JJ);                                             \
    CNT += (unsigned)__popcll(MASK);                                               \
  }

__device__ __forceinline__ void write_row(int r, bool act, u64 L, int lane,
                                          __hip_bfloat16* __restrict__ out) {
  if (lane >= K) return;
  const int o = r * K + lane;
  if (act) {
    out[o] = __float2bfloat16((float)(unsigned)(L & 0xFFFFFFFFull));
    out[N * K + o] = __float2bfloat16(__uint_as_float((unsigned)(L >> 32)));
    out[2 * N * K + o] = __float2bfloat16(1.0f);
  } else {
    out[o] = __float2bfloat16((float)lane);
    ((unsigned short*)out)[N * K + o] = 0x7F7Fu;   // finite bf16-max vs expected inf
    out[2 * N * K + o] = __float2bfloat16(0.0f);
  }
}

// -- main: r5 structure (full stream per wave, 2 rows), approx filter + exact flush,
// -- 4 cands/lane/iter, cheap theta-prime, index-only survivor buffer.            --
__global__ __launch_bounds__(256) void knn_kernel(const float* __restrict__ gx,
                                                  const float* __restrict__ gy,
                                                  const float* __restrict__ gz,
                                                  const float* __restrict__ gw,
                                                  const int* __restrict__ list,
                                                  const int* __restrict__ ctr,
                                                  __hip_bfloat16* __restrict__ out) {
  __shared__ unsigned bufU[NWAVE][R][CAP];

  const int lane = threadIdx.x & 63;
  const int w = threadIdx.x >> 6;
  const int nValid = ctr[0];
  const int pos0 = blockIdx.x * RPB + w * R;
  const int r0 = list[pos0];
  const int r1 = list[pos0 + 1];
  const bool a0 = pos0 < nValid;
  const bool a1 = pos0 + 1 < nValid;

  if (!a0) {                 // whole wave inactive: write defaults + leave
    write_row(r0, false, 0, lane, out);
    write_row(r1, false, 0, lane, out);
    return;
  }

  const float q0x = gx[r0], q0y = gy[r0], q0z = gz[r0], q0w = gw[r0];
  const float q1x = gx[r1], q1y = gy[r1], q1z = gz[r1], q1w = gw[r1];
  const f32x2 q0x2 = {q0x, q0x}, q0y2 = {q0y, q0y}, q0z2 = {q0z, q0z}, q0w2 = {q0w, q0w};
  const f32x2 q1x2 = {q1x, q1x}, q1y2 = {q1y, q1y}, q1z2 = {q1z, q1z}, q1w2 = {q1w, q1w};
  const f32x2 neg2 = {-2.0f, -2.0f};

  u64 L0 = ~0ull, L1 = ~0ull;
  float th0 = __builtin_inff();
  float th1 = a1 ? __builtin_inff() : -__builtin_inff();
  unsigned cnt0 = 0, cnt1 = 0;
  volatile unsigned* b0 = &bufU[w][0][0];
  volatile unsigned* b1 = &bufU[w][1][0];

  const f32x2* BX = (const f32x2*)gx;
  const f32x2* BY = (const f32x2*)gy;
  const f32x2* BZ = (const f32x2*)gz;
  const f32x2* BW = (const f32x2*)gw;

  int ofs = lane;            // f32x2 index of half-A; half-B at +64
  f32x2 aX = BX[ofs], aY = BY[ofs], aZ = BZ[ofs], aW = BW[ofs];
  f32x2 bX = BX[ofs + 64], bY = BY[ofs + 64], bZ = BZ[ofs + 64], bW = BW[ofs + 64];

  for (int it = 0; it < NITER; ++it) {
    const int nofs = (it < NITER - 1) ? ofs + 128 : ofs;     // depth-1 prefetch
    f32x2 naX = BX[nofs], naY = BY[nofs], naZ = BZ[nofs], naW = BW[nofs];
    f32x2 nbX = BX[nofs + 64], nbY = BY[nofs + 64], nbZ = BZ[nofs + 64], nbW = BW[nofs + 64];

    // approx d2' (fma-contracted): 5 pk-ops per (row, 2 cands)
    f32x2 d00 = pk_fma(pk_fma(q0x2, aX, pk_fma(q0y2, aY, pk_mul(q0z2, aZ))), neg2,
                       pk_add(q0w2, aW));
    f32x2 d01 = pk_fma(pk_fma(q0x2, bX, pk_fma(q0y2, bY, pk_mul(q0z2, bZ))), neg2,
                       pk_add(q0w2, bW));
    f32x2 d10 = pk_fma(pk_fma(q1x2, aX, pk_fma(q1y2, aY, pk_mul(q1z2, aZ))), neg2,
                       pk_add(q1w2, aW));
    f32x2 d11 = pk_fma(pk_fma(q1x2, bX, pk_fma(q1y2, bY, pk_mul(q1z2, bZ))), neg2,
                       pk_add(q1w2, bW));

    if (it == 0) {
      // theta-prime: max over lanes of per-lane min d2' bounds the 30th distance
      // (each non-empty lane contributes one real candidate <= the max) — needs
      // >=30 non-empty lanes, else fall back to +inf (burst path, still correct).
      float l0 = fminf(fminf(d00.x, d00.y), fminf(d01.x, d01.y));
      float l1 = fminf(fminf(d10.x, d10.y), fminf(d11.x, d11.y));
      bool e0 = !isinf(l0), e1 = !isinf(l1);
      int n0 = __popcll(__ballot(e0));
      int n1 = __popcll(__ballot(e1));
      float f0 = e0 ? l0 : -__builtin_inff();
      float f1 = e1 ? l1 : -__builtin_inff();
#pragma unroll
      for (int d = 32; d; d >>= 1) {
        f0 = fmaxf(f0, __shfl_xor(f0, d));
        f1 = fmaxf(f1, __shfl_xor(f1, d));
      }
      if (n0 >= 30) th0 = __fadd_rn(__fmul_rn(f0, 1.00001f), 0.02f);
      if (a1 && n1 >= 30) th1 = __fadd_rn(__fmul_rn(f1, 1.00001f), 0.02f);
    }

    bool p00 = d00.x <= th0, p01 = d00.y <= th0, p02 = d01.x <= th0, p03 = d01.y <= th0;
    bool p10 = d10.x <= th1, p11 = d10.y <= th1, p12 = d11.x <= th1, p13 = d11.y <= th1;
    u64 m00 = __ballot(p00), m01 = __ballot(p01), m02 = __ballot(p02), m03 = __ballot(p03);
    u64 m10 = __ballot(p10), m11 = __ballot(p11), m12 = __ballot(p12), m13 = __ballot(p13);

    const unsigned jA = (unsigned)(it * 256 + 2 * lane);     // candidate indices
    const unsigned jB = jA + 128;
    if (m00 | m01 | m02 | m03) {
      PROCESS(b0, cnt0, m00, p00, jA)
      PROCESS(b0, cnt0, m01, p01, jA + 1)
      PROCESS(b0, cnt0, m02, p02, jB)
      PROCESS(b0, cnt0, m03, p03, jB + 1)
      if (cnt0 > FLUSH_AT)
        wave_flush(L0, th0, cnt0, b0, q0x, q0y, q0z, q0w, gx, gy, gz, gw, lane);
    }
    if (m10 | m11 | m12 | m13) {
      PROCESS(b1, cnt1, m10, p10, jA)
      PROCESS(b1, cnt1, m11, p11, jA + 1)
      PROCESS(b1, cnt1, m12, p12, jB)
      PROCESS(b1, cnt1, m13, p13, jB + 1)
      if (cnt1 > FLUSH_AT)
        wave_flush(L1, th1, cnt1, b1, q1x, q1y, q1z, q1w, gx, gy, gz, gw, lane);
    }

    aX = naX; aY = naY; aZ = naZ; aW = naW;
    bX = nbX; bY = nbY; bZ = nbZ; bW = nbW;
    ofs = nofs;
  }

  if (cnt0) wave_flush(L0, th0, cnt0, b0, q0x, q0y, q0z, q0w, gx, gy, gz, gw, lane);
  if (cnt1) wave_flush(L1, th1, cnt1, b1, q1x, q1y, q1z, q1w, gx, gy, gz, gw, lane);

  write_row(r0, true, L0, lane, out);
  write_row(r1, a1, L1, lane, out);
}

extern "C" void kernel_launch(void* const* d_in, const int* in_sizes, int n_in,
                              void* d_out, int out_size, void* d_ws, size_t ws_size,
                              hipStream_t stream) {
  const float* X = (const float*)d_in[0];
  const int* C = (const int*)d_in[1];
  float* gx = (float*)d_ws;
  float* gy = (float*)((char*)d_ws + 32768);
  float* gz = (float*)((char*)d_ws + 65536);
  float* gw = (float*)((char*)d_ws + 98304);
  int* list = (int*)((char*)d_ws + 131072);
  int* ctr = (int*)((char*)d_ws + 163840);
  __hip_bfloat16* out = (__hip_bfloat16*)d_out;

  zero_kernel<<<1, 64, 0, stream>>>(ctr);
  prep_kernel<<<N / 256, 256, 0, stream>>>(X, C, gx, gy, gz, gw, list, ctr);
  knn_kernel<<<N / RPB, 256, 0, stream>>>(gx, gy, gz, gw, list, ctr, out);
}

// Round 11
// 71.671 us; speedup vs baseline: 1.4809x; 1.3415x over previous
//
#include <hip/hip_runtime.h>
#include <hip/hip_bf16.h>
#include <stdint.h>

typedef unsigned long long u64;
typedef float f32x2 __attribute__((ext_vector_type(2)));

#define N 8192
#define K 30
#define NWAVE 4                 // waves per block (256 threads)
#define R 2                     // rows per wave
#define RPB (NWAVE * R)         // rows per block = 8
#define CAP 320                 // 5 slots * 64 lanes
#define FLUSH_AT 192            // flush when cnt > 192 (influx <= 128/iter -> <= 320)

// ws layout: gx[8192] @0 | gy @32768 | gz @65536 | gw @98304 | list @131072 | ctr @163840

// CDNA packed-f32 (VOP3P): pk_mul/pk_add/pk_fma exist on gfx950; pk_max does NOT.
static __device__ __forceinline__ f32x2 pk_mul(f32x2 a, f32x2 b) {
  f32x2 d; asm("v_pk_mul_f32 %0, %1, %2" : "=v"(d) : "v"(a), "v"(b)); return d;
}
static __device__ __forceinline__ f32x2 pk_add(f32x2 a, f32x2 b) {
  f32x2 d; asm("v_pk_add_f32 %0, %1, %2" : "=v"(d) : "v"(a), "v"(b)); return d;
}
static __device__ __forceinline__ f32x2 pk_fma(f32x2 a, f32x2 b, f32x2 c) {
  f32x2 d; asm("v_pk_fma_f32 %0, %1, %2, %3" : "=v"(d) : "v"(a), "v"(b), "v"(c)); return d;
}
// component-wise clamp to >=0 (two v_max_f32; exact, matches jnp.maximum(d2,0))
static __device__ __forceinline__ f32x2 clamp0(f32x2 a) {
  f32x2 d; d.x = fmaxf(a.x, 0.0f); d.y = fmaxf(a.y, 0.0f); return d;
}

__global__ void zero_kernel(int* __restrict__ ctr) {
  if (threadIdx.x < 2) ctr[threadIdx.x] = 0;
}

// ---------------- prep: centroid + sq + validity (SoA), compact row list ----------
// _rn intrinsics: no FMA contraction, bit-match np f32.
__global__ __launch_bounds__(256) void prep_kernel(const float* __restrict__ X,
                                                   const int* __restrict__ C,
                                                   float* __restrict__ gx,
                                                   float* __restrict__ gy,
                                                   float* __restrict__ gz,
                                                   float* __restrict__ gw,
                                                   int* __restrict__ list,
                                                   int* __restrict__ ctr) {
  int i = blockIdx.x * 256 + threadIdx.x;
  if (i >= N) return;
  const float4* xp = (const float4*)(X + (size_t)i * 12);
  float4 f0 = xp[0], f1 = xp[1], f2 = xp[2];
  float mx = __fmul_rn(__fadd_rn(__fadd_rn(__fadd_rn(f0.x, f0.w), f1.z), f2.y), 0.25f);
  float my = __fmul_rn(__fadd_rn(__fadd_rn(__fadd_rn(f0.y, f1.x), f1.w), f2.z), 0.25f);
  float mz = __fmul_rn(__fadd_rn(__fadd_rn(__fadd_rn(f0.z, f1.y), f2.x), f2.w), 0.25f);
  float sq = __fadd_rn(__fadd_rn(__fmul_rn(mx, mx), __fmul_rn(my, my)), __fmul_rn(mz, mz));
  bool valid = (C[i] > 0);
  gx[i] = mx; gy[i] = my; gz[i] = mz;
  gw[i] = valid ? sq : __builtin_inff();
  if (valid) { int p = atomicAdd(&ctr[0], 1); list[p] = i; }
  else       { int p = atomicAdd(&ctr[1], 1); list[N - 1 - p] = i; }
}

// ---------------- bitonic helpers (validated rounds 2-9; final phase ONLY) --------
static __device__ __forceinline__ u64 sort64(u64 v, int lane) {
#pragma unroll
  for (int kk = 2; kk <= 64; kk <<= 1) {
#pragma unroll
    for (int j = kk >> 1; j > 0; j >>= 1) {
      u64 o = __shfl_xor(v, j);
      bool lower = (lane & j) == 0;
      bool asc = (lane & kk) == 0;
      u64 mn = v < o ? v : o;
      u64 mx = v < o ? o : v;
      v = (lower == asc) ? mn : mx;
    }
  }
  return v;
}
static __device__ __forceinline__ u64 merge64(u64 L, u64 v, int lane) {
  u64 vr = __shfl(v, 63 - lane);
  u64 m = L < vr ? L : vr;
#pragma unroll
  for (int j = 32; j > 0; j >>= 1) {
    u64 o = __shfl_xor(m, j);
    bool lower = (lane & j) == 0;
    u64 mn = m < o ? m : o;
    u64 mx = m < o ? o : m;
    m = lower ? mn : mx;
  }
  return m;
}

// -------- radix flush: theta via 16-round bit search (no shuffle chains), purge ----
// buf entries: (clamped_d2_bits<<32)|idx. Non-negative floats: uint order = value order.
// theta = smallest 2^16-granule upper bound with count(<theta) >= 30  =>  theta >= true
// 30th of everything processed so far (superset-safe); purge keeps entries < theta.
__device__ __forceinline__ void radix_flush(float& th, unsigned& cnt, u64* bufp,
                                            int lane, u64 lmlt) {
  u64 e0 = (unsigned)(lane)       < cnt ? bufp[lane]       : ~0ull;
  u64 e1 = (unsigned)(lane + 64)  < cnt ? bufp[lane + 64]  : ~0ull;
  u64 e2 = (unsigned)(lane + 128) < cnt ? bufp[lane + 128] : ~0ull;
  u64 e3 = (unsigned)(lane + 192) < cnt ? bufp[lane + 192] : ~0ull;
  u64 e4 = (unsigned)(lane + 256) < cnt ? bufp[lane + 256] : ~0ull;
  unsigned h0 = (unsigned)(e0 >> 32), h1 = (unsigned)(e1 >> 32);
  unsigned h2 = (unsigned)(e2 >> 32), h3 = (unsigned)(e3 >> 32);
  unsigned h4 = (unsigned)(e4 >> 32);

  unsigned piv = 0;
#pragma unroll
  for (int b = 15; b >= 0; --b) {
    unsigned cand = piv + (0x10000u << b);
    int c = __popcll(__ballot(h0 < cand)) + __popcll(__ballot(h1 < cand)) +
            __popcll(__ballot(h2 < cand)) + __popcll(__ballot(h3 < cand)) +
            __popcll(__ballot(h4 < cand));
    if (c < K) piv = cand;           // invariant: count(< piv) < K
  }
  if (piv < 0xFFFF0000u)             // guard overflow (cannot trigger w/ >=30 finite)
    th = fminf(th, __uint_as_float(piv + 0x10000u));

  const unsigned thb = __float_as_uint(th);
  unsigned total = 0;
#define PURGE_SLOT(E, H)                                                      \
  { u64 mk = __ballot((H) < thb);                                             \
    if (mk) {                                                                 \
      unsigned pos = total + (unsigned)__popcll(mk & lmlt);                   \
      if ((H) < thb) bufp[pos] = (E);                                         \
      total += (unsigned)__popcll(mk); } }
  PURGE_SLOT(e0, h0)
  PURGE_SLOT(e1, h1)
  PURGE_SLOT(e2, h2)
  PURGE_SLOT(e3, h3)
  PURGE_SLOT(e4, h4)
#undef PURGE_SLOT
  cnt = total;
}

// -------- final: tighten+purge, then ONE exact bitonic pass over ~30-60 survivors --
// D = sqrt(d2c + 1e-6) with d2c = fmax(d2,0) already exact  =>  exact ref formula.
__device__ __forceinline__ u64 finalize_row(float& th, unsigned& cnt, u64* bufp,
                                            int lane, u64 lmlt) {
  radix_flush(th, cnt, bufp, lane, lmlt);
  u64 L = ~0ull;
  for (unsigned base = 0; base < cnt; base += 64) {
    u64 v = ~0ull;
    if (base + (unsigned)lane < cnt) {
      u64 raw = bufp[base + lane];
      float d2c = __uint_as_float((unsigned)(raw >> 32));
      float D = sqrtf(__fadd_rn(d2c, 1e-6f));
      v = ((u64)__float_as_uint(D) << 32) | (raw & 0xFFFFFFFFull);
    }
    v = sort64(v, lane);
    L = merge64(L, v, lane);
  }
  return L;
}

#define PACK(V, J) (((u64)__float_as_uint(V) << 32) | (unsigned)(J))
#define PROCESS(BUF, CNT, MASK, D2V, JJ)                                       \
  if (MASK) {                                                                  \
    unsigned pos = CNT + (unsigned)__popcll((MASK) & lmlt);                    \
    if (((MASK) >> lane) & 1ull) (BUF)[pos] = PACK(D2V, JJ);                   \
    CNT += (unsigned)__popcll(MASK);                                           \
  }

__device__ __forceinline__ void write_row(int r, bool act, u64 L, int lane,
                                          __hip_bfloat16* __restrict__ out) {
  if (lane >= K) return;
  const int o = r * K + lane;
  if (act) {
    out[o] = __float2bfloat16((float)(unsigned)(L & 0xFFFFFFFFull));
    out[N * K + o] = __float2bfloat16(__uint_as_float((unsigned)(L >> 32)));
    out[2 * N * K + o] = __float2bfloat16(1.0f);
  } else {
    out[o] = __float2bfloat16((float)lane);
    ((unsigned short*)out)[N * K + o] = 0x7F7Fu;   // finite bf16-max vs expected inf
    out[2 * N * K + o] = __float2bfloat16(0.0f);
  }
}

// -- main: r5 streaming structure (proven), radix-select flush (no mid-loop sorts) --
__global__ __launch_bounds__(256) void knn_kernel(const float* __restrict__ gx,
                                                  const float* __restrict__ gy,
                                                  const float* __restrict__ gz,
                                                  const float* __restrict__ gw,
                                                  const int* __restrict__ list,
                                                  const int* __restrict__ ctr,
                                                  __hip_bfloat16* __restrict__ out) {
  __shared__ u64 bufS[NWAVE][R][CAP];

  const int lane = threadIdx.x & 63;
  const int w = threadIdx.x >> 6;
  const u64 lmlt = (1ull << lane) - 1ull;
  const int nValid = ctr[0];
  const int pos0 = blockIdx.x * RPB + w * R;
  const int r0 = list[pos0];
  const int r1 = list[pos0 + 1];
  const bool a0 = pos0 < nValid;
  const bool a1 = pos0 + 1 < nValid;

  if (!a0) {                 // whole wave inactive: write defaults + leave
    write_row(r0, false, 0, lane, out);
    write_row(r1, false, 0, lane, out);
    return;
  }

  const float q0x = gx[r0], q0y = gy[r0], q0z = gz[r0], q0w = gw[r0];
  const float q1x = gx[r1], q1y = gy[r1], q1z = gz[r1], q1w = gw[r1];
  const f32x2 q0x2 = {q0x, q0x}, q0y2 = {q0y, q0y}, q0z2 = {q0z, q0z}, q0w2 = {q0w, q0w};
  const f32x2 q1x2 = {q1x, q1x}, q1y2 = {q1y, q1y}, q1z2 = {q1z, q1z}, q1w2 = {q1w, q1w};
  const f32x2 neg1 = {-1.0f, -1.0f};

  float th0 = __builtin_inff();
  float th1 = a1 ? __builtin_inff() : -__builtin_inff();  // inactive row1 never accepts
  unsigned cnt0 = 0, cnt1 = 0;
  u64* b0 = &bufS[w][0][0];
  u64* b1 = &bufS[w][1][0];

  const f32x2* bx = (const f32x2*)gx;
  const f32x2* by = (const f32x2*)gy;
  const f32x2* bz = (const f32x2*)gz;
  const f32x2* bw = (const f32x2*)gw;

  int idx = lane;                       // f32x2 index
  f32x2 px = bx[idx], py = by[idx], pz = bz[idx], pw = bw[idx];

#pragma unroll 2
  for (int it = 0; it < 64; ++it) {
    const int nidx = (it < 63) ? idx + 64 : idx;          // depth-1 prefetch
    f32x2 nx = bx[nidx], ny = by[nidx], nz = bz[nidx], nw = bw[nidx];

    // exact np f32 rounding: dot=(qx*px+qy*py)+qz*pz; 2*dot==dot+dot (exact);
    // t-u via fma(u,-1,t) == fsub_rn; clamp fmax(d2,0) exact (non-neg bits order).
    f32x2 dot0 = pk_add(pk_add(pk_mul(q0x2, px), pk_mul(q0y2, py)), pk_mul(q0z2, pz));
    f32x2 d20 = clamp0(pk_fma(pk_add(dot0, dot0), neg1, pk_add(q0w2, pw)));
    f32x2 dot1 = pk_add(pk_add(pk_mul(q1x2, px), pk_mul(q1y2, py)), pk_mul(q1z2, pz));
    f32x2 d21 = clamp0(pk_fma(pk_add(dot1, dot1), neg1, pk_add(q1w2, pw)));
    u64 me0 = __ballot(d20.x <= th0);
    u64 mo0 = __ballot(d20.y <= th0);
    u64 me1 = __ballot(d21.x <= th1);
    u64 mo1 = __ballot(d21.y <= th1);
    if (me0 | mo0 | me1 | mo1) {
      const int jb = 2 * idx;           // global candidate index (even slot)
      if (me0 | mo0) {
        PROCESS(b0, cnt0, me0, d20.x, jb)
        PROCESS(b0, cnt0, mo0, d20.y, jb + 1)
        if (cnt0 > FLUSH_AT) radix_flush(th0, cnt0, b0, lane, lmlt);
      }
      if (me1 | mo1) {
        PROCESS(b1, cnt1, me1, d21.x, jb)
        PROCESS(b1, cnt1, mo1, d21.y, jb + 1)
        if (cnt1 > FLUSH_AT) radix_flush(th1, cnt1, b1, lane, lmlt);
      }
    }
    px = nx; py = ny; pz = nz; pw = nw;
    idx = nidx;
  }

  u64 L0 = finalize_row(th0, cnt0, b0, lane, lmlt);
  u64 L1 = a1 ? finalize_row(th1, cnt1, b1, lane, lmlt) : ~0ull;

  write_row(r0, true, L0, lane, out);
  write_row(r1, a1, L1, lane, out);
}

extern "C" void kernel_launch(void* const* d_in, const int* in_sizes, int n_in,
                              void* d_out, int out_size, void* d_ws, size_t ws_size,
                              hipStream_t stream) {
  const float* X = (const float*)d_in[0];
  const int* C = (const int*)d_in[1];
  float* gx = (float*)d_ws;
  float* gy = (float*)((char*)d_ws + 32768);
  float* gz = (float*)((char*)d_ws + 65536);
  float* gw = (float*)((char*)d_ws + 98304);
  int* list = (int*)((char*)d_ws + 131072);
  int* ctr = (int*)((char*)d_ws + 163840);
  __hip_bfloat16* out = (__hip_bfloat16*)d_out;

  zero_kernel<<<1, 64, 0, stream>>>(ctr);
  prep_kernel<<<N / 256, 256, 0, stream>>>(X, C, gx, gy, gz, gw, list, ctr);
  knn_kernel<<<N / RPB, 256, 0, stream>>>(gx, gy, gz, gw, list, ctr, out);
}